// Round 6
// baseline (964.836 us; speedup 1.0000x reference)
//
#include <hip/hip_runtime.h>
#include <hip/hip_bf16.h>

#define NB 2
#define CH 256
#define HS 96
#define HW 9216
#define CHW 2359296      // 256*9216
#define INNER 14
#define NF 252
#define SL2E 0.09016844f // (1/sqrt(256)) * log2(e)

using f32x4 = __attribute__((ext_vector_type(4))) float;
using s16x8 = __attribute__((ext_vector_type(8))) short;

__device__ __forceinline__ void gload_lds16(const unsigned short* g, unsigned short* l) {
    __builtin_amdgcn_global_load_lds(
        (const __attribute__((address_space(1))) unsigned int*)g,
        (__attribute__((address_space(3))) unsigned int*)l,
        16, 0, 0);
}

// ---------------- 1x1 conv (GEMM): 32 couts/block, 2 pixels/thread ----------
template<int CIN, typename OT>
__global__ __launch_bounds__(256)
void k_conv1x1(const float* __restrict__ in, const float* __restrict__ w,
               const float* __restrict__ bias, OT* __restrict__ out) {
    __shared__ float wsh[CIN][32];
    const int tid = threadIdx.x;
    const int coB = blockIdx.y * 32;
    for (int e = tid; e < CIN * 32; e += 256) {
        int ci = e >> 5, col = e & 31;
        wsh[ci][col] = w[(coB + col) * CIN + ci];
    }
    __syncthreads();
    const int P0  = blockIdx.x * 512 + tid;
    const int b   = P0 / HW;
    const int pp0 = P0 - b * HW;
    const int pp1 = pp0 + 256;
    const float* inb = in + (size_t)b * CIN * HW;
    float acc0[32], acc1[32];
    #pragma unroll
    for (int j = 0; j < 32; ++j) { acc0[j] = 0.f; acc1[j] = 0.f; }
    for (int ci = 0; ci < CIN; ++ci) {
        float x0 = inb[(size_t)ci * HW + pp0];
        float x1 = inb[(size_t)ci * HW + pp1];
        const float4* wr = (const float4*)wsh[ci];
        #pragma unroll
        for (int q = 0; q < 8; ++q) {
            float4 wv = wr[q];
            acc0[q*4+0] += wv.x*x0; acc0[q*4+1] += wv.y*x0;
            acc0[q*4+2] += wv.z*x0; acc0[q*4+3] += wv.w*x0;
            acc1[q*4+0] += wv.x*x1; acc1[q*4+1] += wv.y*x1;
            acc1[q*4+2] += wv.z*x1; acc1[q*4+3] += wv.w*x1;
        }
    }
    OT* ob = out + (size_t)b * CH * HW;
    #pragma unroll
    for (int j = 0; j < 32; ++j) {
        float bv = bias[coB + j];
        ob[(size_t)(coB + j) * HW + pp0] = (OT)(acc0[j] + bv);
        ob[(size_t)(coB + j) * HW + pp1] = (OT)(acc1[j] + bv);
    }
}

// ------- reduce: 256 -> 14 channels; 64 px/block, 4-way channel split -------
__global__ __launch_bounds__(256)
void k_reduce(const float* __restrict__ fmap, const float* __restrict__ w,
              const float* __restrict__ bias, float* __restrict__ xr) {
    __shared__ float wsh[256][16];
    __shared__ float part[4][64][17];
    const int tid = threadIdx.x;
    for (int e = tid; e < 256 * 16; e += 256) {
        int ci = e >> 4, co = e & 15;
        wsh[ci][co] = (co < INNER) ? w[co * 256 + ci] : 0.f;
    }
    __syncthreads();
    const int px  = tid & 63, grp = tid >> 6;
    const int Pb  = blockIdx.x * 64;          // 64-aligned, never crosses batch
    const int b   = Pb / HW;
    const int ppb = Pb - b * HW;
    const float* fb = fmap + (size_t)b * CHW + (size_t)(grp * 64) * HW + ppb + px;
    float acc[16];
    #pragma unroll
    for (int j = 0; j < 16; ++j) acc[j] = 0.f;
    for (int ci = 0; ci < 64; ++ci) {
        float xv = fb[(size_t)ci * HW];
        const float4* wr = (const float4*)wsh[grp * 64 + ci];
        #pragma unroll
        for (int q = 0; q < 4; ++q) {
            float4 wv = wr[q];
            acc[q*4+0] += wv.x*xv; acc[q*4+1] += wv.y*xv;
            acc[q*4+2] += wv.z*xv; acc[q*4+3] += wv.w*xv;
        }
    }
    #pragma unroll
    for (int j = 0; j < 16; ++j) part[grp][px][j] = acc[j];
    __syncthreads();
    for (int e = tid; e < 64 * INNER; e += 256) {
        int co = e >> 6, p2 = e & 63;
        float v = part[0][p2][co] + part[1][p2][co] + part[2][p2][co] +
                  part[3][p2][co] + bias[co];
        xr[(size_t)(b * INNER + co) * HW + ppb + p2] = v;
    }
}

// ------- dilated 3x3 conv + 6 spatial-transform products -> feats (252 ch) ----
__global__ __launch_bounds__(256)
void k_dil(const float* __restrict__ xr, const float* __restrict__ dw,
           const float* __restrict__ db, float* __restrict__ feats) {
    int bid = blockIdx.x;
    const int hb = bid % 36; bid /= 36;
    const int oc = bid % 14; bid /= 14;
    const int b  = bid & 1;  bid >>= 1;
    const int d  = bid;              // 0..2
    const int dil = d + 1;
    __shared__ float wsh[126];
    const int tid = threadIdx.x;
    if (tid < 126) wsh[tid] = dw[(d * 14 + oc) * 126 + tid];
    __syncthreads();
    const int p = hb * 256 + tid;
    const int h = p / 96, w = p - (p / 96) * 96;
    const float* xb = xr + (size_t)b * INNER * HW;
    float acc = db[d * 14 + oc];
    for (int ic = 0; ic < 14; ++ic) {
        const float* xc = xb + (size_t)ic * HW;
        #pragma unroll
        for (int kh = 0; kh < 3; ++kh) {
            int ih = h + (kh - 1) * dil;
            if (ih < 0 || ih >= 96) continue;
            #pragma unroll
            for (int kw = 0; kw < 3; ++kw) {
                int iw = w + (kw - 1) * dil;
                if (iw < 0 || iw >= 96) continue;
                acc += xc[ih * 96 + iw] * wsh[ic * 9 + kh * 3 + kw];
            }
        }
    }
    const float* xo = xb + (size_t)oc * HW;
    const int H1 = 95;
    float t0 = xo[h * 96 + w];
    float t1 = xo[h * 96 + (H1 - w)];
    float t2 = xo[(H1 - h) * 96 + w];
    float t3 = xo[w * 96 + (H1 - h)];
    float t4 = xo[(H1 - h) * 96 + (H1 - w)];
    float t5 = xo[(H1 - w) * 96 + h];
    float* fo = feats + (size_t)b * NF * HW;
    const int ch0 = d * 6 * 14 + oc;
    fo[(size_t)(ch0 + 0 * 14) * HW + p] = acc * t0;
    fo[(size_t)(ch0 + 1 * 14) * HW + p] = acc * t1;
    fo[(size_t)(ch0 + 2 * 14) * HW + p] = acc * t2;
    fo[(size_t)(ch0 + 3 * 14) * HW + p] = acc * t3;
    fo[(size_t)(ch0 + 4 * 14) * HW + p] = acc * t4;
    fo[(size_t)(ch0 + 5 * 14) * HW + p] = acc * t5;
}

// ------- transpose: tok_c bf16 [C][HW] -> tok_t bf16 [HW][C] -------
__global__ __launch_bounds__(256)
void k_tr(const unsigned short* __restrict__ tc, unsigned short* __restrict__ tt) {
    const int tid = threadIdx.x;
    int bid = blockIdx.x;
    const int b = bid / 576;
    const int r = bid - b * 576;          // 0..575
    const int t0 = (r >> 2) * 64;
    const int c0 = (r & 3) * 64;
    __shared__ unsigned int T[64][37];
    const unsigned short* tcb = tc + (size_t)b * CHW;
    unsigned short* ttb = tt + (size_t)b * CHW;
    for (int e = tid; e < 2048; e += 256) {
        int to = e & 63, chp = e >> 6;    // chp 0..31 (pair of channels)
        unsigned int v0 = tcb[(size_t)(c0 + 2*chp)     * HW + t0 + to];
        unsigned int v1 = tcb[(size_t)(c0 + 2*chp + 1) * HW + t0 + to];
        T[to][chp] = (v1 << 16) | v0;
    }
    __syncthreads();
    for (int e = tid; e < 2048; e += 256) {
        int to = e >> 5, chp = e & 31;
        ((unsigned int*)(ttb + (size_t)(t0 + to) * CH + c0))[chp] = T[to][chp];
    }
}

// ---------------- bf16 MFMA flash attention + residual ----------------
// 288 blocks, 256 thr (4 waves x 16 q), KV tile 64 keys, D=256.
// Double-buffered LDS staged via global_load_lds (pre-swizzled source),
// one barrier per tile; exp2-domain softmax with defer-max.
#define KTILE 64
#define NKT 144

__device__ __forceinline__ unsigned int pk_bf16(float lo, float hi) {
    unsigned int l = __bfloat16_as_ushort(__float2bfloat16(lo));
    unsigned int h = __bfloat16_as_ushort(__float2bfloat16(hi));
    return (h << 16) | l;
}

__global__ __launch_bounds__(256, 1)
void k_attn2(const unsigned short* __restrict__ tok_t,
             const unsigned short* __restrict__ tok_c,
             const float* __restrict__ fmap, float* __restrict__ outp) {
    __shared__ unsigned short Kt[2][64][256];   // [key][ch ^ ((key&7)<<3)]
    __shared__ unsigned short Vt[2][256][64];   // [ch][key ^ ((ch&7)<<3)]
    __shared__ unsigned short Psh[4][16][72];   // per-wave [q][key]
    const int tid  = threadIdx.x;
    const int wid  = tid >> 6;
    const int lane = tid & 63;
    const int lq   = lane & 15;
    const int lg   = lane >> 4;

    const int blk = blockIdx.x;
    const int qb  = (blk & 7) * 36 + (blk >> 3);   // XCD-grouped
    const int b   = qb / 144;
    const int q0  = (qb - b * 144) * 64;
    const unsigned short* tt = tok_t + (size_t)b * CHW;
    const unsigned short* tc = tok_c + (size_t)b * CHW;

    // per-thread staging offsets (pre-swizzled source, linear LDS dest)
    int koff[8], voff[8];
    #pragma unroll
    for (int i = 0; i < 8; ++i) {
        int c   = i * 256 + tid;
        int key = c >> 5, sc = c & 31;
        koff[i] = key * CH + ((sc ^ (key & 7)) << 3);
        int ch  = c >> 3, sv = c & 7;
        voff[i] = ch * HW + ((sv ^ (ch & 7)) << 3);
    }
    unsigned short* KtF = &Kt[0][0][0];
    unsigned short* VtF = &Vt[0][0][0];

    // Q fragments (B-operand of S^T): col=q=lq, k = ks*32 + 8*lg + j
    s16x8 qf[8];
    {
        const unsigned short* qrow = tt + (size_t)(q0 + wid*16 + lq) * CH + 8*lg;
        #pragma unroll
        for (int ks = 0; ks < 8; ++ks)
            qf[ks] = *(const s16x8*)(qrow + 32*ks);
    }
    float m_r = -1e30f, l_r = 0.f;
    f32x4 oacc[16];
    #pragma unroll
    for (int ct = 0; ct < 16; ++ct) oacc[ct] = (f32x4){0.f,0.f,0.f,0.f};

    // prologue: stage tile 0 into buf 0
    #pragma unroll
    for (int i = 0; i < 8; ++i) {
        int c = i * 256 + tid;
        gload_lds16(tt + koff[i], KtF + c * 8);
        gload_lds16(tc + voff[i], VtF + c * 8);
    }
    __syncthreads();

    int cur = 0;
    for (int t = 0; t < NKT; ++t) {
        // issue next tile's loads (land in other buffer; drained at barrier)
        if (t + 1 < NKT) {
            const int kn = (t + 1) * KTILE;
            const unsigned short* tk = tt + (size_t)kn * CH;
            const unsigned short* tv = tc + kn;
            unsigned short* kd = KtF + (cur ^ 1) * 16384;
            unsigned short* vd = VtF + (cur ^ 1) * 16384;
            #pragma unroll
            for (int i = 0; i < 8; ++i) {
                int c = i * 256 + tid;
                gload_lds16(tk + koff[i], kd + c * 8);
                gload_lds16(tv + voff[i], vd + c * 8);
            }
        }
        // ---- S^T = K·Q^T : 4 key-subtiles ----
        float s[16];
        #pragma unroll
        for (int mt = 0; mt < 4; ++mt) {
            f32x4 acc = (f32x4){0.f,0.f,0.f,0.f};
            const int key = mt * 16 + lq;
            const int sw  = (key & 7) << 3;
            #pragma unroll
            for (int ks = 0; ks < 8; ++ks) {
                s16x8 af = *(const s16x8*)(&Kt[cur][key][(ks*32 + 8*lg) ^ sw]);
                acc = __builtin_amdgcn_mfma_f32_16x16x32_bf16(af, qf[ks], acc, 0, 0, 0);
            }
            #pragma unroll
            for (int r = 0; r < 4; ++r) s[mt*4 + r] = acc[r] * SL2E;
        }
        // ---- online softmax (exp2 domain, defer-max) ----
        float tm = s[0];
        #pragma unroll
        for (int i = 1; i < 16; ++i) tm = fmaxf(tm, s[i]);
        tm = fmaxf(tm, __shfl_xor(tm, 16));
        tm = fmaxf(tm, __shfl_xor(tm, 32));
        const float mn = fmaxf(m_r, tm);
        if (!__all(mn - m_r <= 8.0f)) {
            const float alpha = exp2f(m_r - mn);
            m_r = mn;
            l_r *= alpha;
            #pragma unroll
            for (int ct = 0; ct < 16; ++ct) {
                oacc[ct][0] *= alpha; oacc[ct][1] *= alpha;
                oacc[ct][2] *= alpha; oacc[ct][3] *= alpha;
            }
        }
        float ps = 0.f;
        #pragma unroll
        for (int i = 0; i < 16; ++i) { s[i] = exp2f(s[i] - m_r); ps += s[i]; }
        ps += __shfl_xor(ps, 16);
        ps += __shfl_xor(ps, 32);
        l_r += ps;
        // ---- P -> per-wave LDS (keys 16*kt + 4*lg + r at row q=lq) ----
        #pragma unroll
        for (int kt = 0; kt < 4; ++kt) {
            *(unsigned int*)&Psh[wid][lq][16*kt + 4*lg]     = pk_bf16(s[kt*4+0], s[kt*4+1]);
            *(unsigned int*)&Psh[wid][lq][16*kt + 4*lg + 2] = pk_bf16(s[kt*4+2], s[kt*4+3]);
        }
        s16x8 pb0 = *(const s16x8*)&Psh[wid][lq][8*lg];
        s16x8 pb1 = *(const s16x8*)&Psh[wid][lq][32 + 8*lg];
        // ---- PV: out^T[ch][q], A = V^T frags from Vt ----
        #pragma unroll
        for (int ct = 0; ct < 16; ++ct) {
            const int ch = ct * 16 + lq;
            const int sw = (ch & 7) << 3;
            s16x8 va0 = *(const s16x8*)(&Vt[cur][ch][(8*lg) ^ sw]);
            s16x8 va1 = *(const s16x8*)(&Vt[cur][ch][(32 + 8*lg) ^ sw]);
            oacc[ct] = __builtin_amdgcn_mfma_f32_16x16x32_bf16(va0, pb0, oacc[ct], 0, 0, 0);
            oacc[ct] = __builtin_amdgcn_mfma_f32_16x16x32_bf16(va1, pb1, oacc[ct], 0, 0, 0);
        }
        __syncthreads();     // drains next-tile loads; all waves done with cur
        cur ^= 1;
    }
    // ---- epilogue: normalize + residual, direct write ----
    const float linv = 1.f / l_r;
    const float* fb = fmap + (size_t)b * CHW;
    float* ob = outp + (size_t)b * CHW;
    const int qg = q0 + wid * 16 + lq;
    #pragma unroll
    for (int ct = 0; ct < 16; ++ct)
        #pragma unroll
        for (int cr = 0; cr < 4; ++cr) {
            const int ch = ct * 16 + 4 * lg + cr;
            const size_t g = (size_t)ch * HW + qg;
            ob[g] = fb[g] + 0.2f * (oacc[ct][cr] * linv);
        }
}

extern "C" void kernel_launch(void* const* d_in, const int* in_sizes, int n_in,
                              void* d_out, int out_size, void* d_ws, size_t ws_size,
                              hipStream_t stream) {
    const float* x        = (const float*)d_in[0];
    const float* proj_w   = (const float*)d_in[1];
    const float* proj_b   = (const float*)d_in[2];
    const float* reduce_w = (const float*)d_in[3];
    const float* reduce_b = (const float*)d_in[4];
    const float* dil_w    = (const float*)d_in[5];
    const float* dil_b    = (const float*)d_in[6];
    const float* fuse_w   = (const float*)d_in[7];
    const float* fuse_b   = (const float*)d_in[8];
    float* out = (float*)d_out;

    float* ws    = (float*)d_ws;
    float* fmap  = ws;                           // 4,718,592 f
    float* xr    = fmap + 4718592;               //   258,048 f
    float* feats = xr + 258048;                  // 4,644,864 f
    unsigned short* tok_c = (unsigned short*)(feats + 4644864);   // 4,718,592 u16
    unsigned short* tok_t = tok_c + 4718592;                      // 4,718,592 u16

    k_conv1x1<256, float><<<dim3(36, 8), 256, 0, stream>>>(x, proj_w, proj_b, fmap);
    k_reduce<<<288, 256, 0, stream>>>(fmap, reduce_w, reduce_b, xr);
    k_dil<<<3024, 256, 0, stream>>>(xr, dil_w, dil_b, feats);
    k_conv1x1<252, __hip_bfloat16><<<dim3(36, 8), 256, 0, stream>>>(
        feats, fuse_w, fuse_b, (__hip_bfloat16*)tok_c);
    k_tr<<<1152, 256, 0, stream>>>(tok_c, tok_t);
    k_attn2<<<288, 256, 0, stream>>>(tok_t, tok_c, fmap, out);
}

// Round 7
// 735.788 us; speedup vs baseline: 1.3113x; 1.3113x over previous
//
#include <hip/hip_runtime.h>
#include <hip/hip_bf16.h>

#define NB 2
#define CH 256
#define HS 96
#define HW 9216
#define CHW 2359296      // 256*9216
#define INNER 14
#define NF 252
#define SL2E 0.09016844f // (1/sqrt(256)) * log2(e)

using f32x4 = __attribute__((ext_vector_type(4))) float;
using s16x8 = __attribute__((ext_vector_type(8))) short;

// ---------------- 1x1 conv (GEMM): 32 couts/block, 2 pixels/thread ----------
template<int CIN, typename OT>
__global__ __launch_bounds__(256)
void k_conv1x1(const float* __restrict__ in, const float* __restrict__ w,
               const float* __restrict__ bias, OT* __restrict__ out) {
    __shared__ float wsh[CIN][32];
    const int tid = threadIdx.x;
    const int coB = blockIdx.y * 32;
    for (int e = tid; e < CIN * 32; e += 256) {
        int ci = e >> 5, col = e & 31;
        wsh[ci][col] = w[(coB + col) * CIN + ci];
    }
    __syncthreads();
    const int P0  = blockIdx.x * 512 + tid;
    const int b   = P0 / HW;
    const int pp0 = P0 - b * HW;
    const int pp1 = pp0 + 256;
    const float* inb = in + (size_t)b * CIN * HW;
    float acc0[32], acc1[32];
    #pragma unroll
    for (int j = 0; j < 32; ++j) { acc0[j] = 0.f; acc1[j] = 0.f; }
    for (int ci = 0; ci < CIN; ++ci) {
        float x0 = inb[(size_t)ci * HW + pp0];
        float x1 = inb[(size_t)ci * HW + pp1];
        const float4* wr = (const float4*)wsh[ci];
        #pragma unroll
        for (int q = 0; q < 8; ++q) {
            float4 wv = wr[q];
            acc0[q*4+0] += wv.x*x0; acc0[q*4+1] += wv.y*x0;
            acc0[q*4+2] += wv.z*x0; acc0[q*4+3] += wv.w*x0;
            acc1[q*4+0] += wv.x*x1; acc1[q*4+1] += wv.y*x1;
            acc1[q*4+2] += wv.z*x1; acc1[q*4+3] += wv.w*x1;
        }
    }
    OT* ob = out + (size_t)b * CH * HW;
    #pragma unroll
    for (int j = 0; j < 32; ++j) {
        float bv = bias[coB + j];
        ob[(size_t)(coB + j) * HW + pp0] = (OT)(acc0[j] + bv);
        ob[(size_t)(coB + j) * HW + pp1] = (OT)(acc1[j] + bv);
    }
}

// ------- reduce: 256 -> 14 channels; 64 px/block, 4-way channel split -------
__global__ __launch_bounds__(256)
void k_reduce(const float* __restrict__ fmap, const float* __restrict__ w,
              const float* __restrict__ bias, float* __restrict__ xr) {
    __shared__ float wsh[256][16];
    __shared__ float part[4][64][17];
    const int tid = threadIdx.x;
    for (int e = tid; e < 256 * 16; e += 256) {
        int ci = e >> 4, co = e & 15;
        wsh[ci][co] = (co < INNER) ? w[co * 256 + ci] : 0.f;
    }
    __syncthreads();
    const int px  = tid & 63, grp = tid >> 6;
    const int Pb  = blockIdx.x * 64;
    const int b   = Pb / HW;
    const int ppb = Pb - b * HW;
    const float* fb = fmap + (size_t)b * CHW + (size_t)(grp * 64) * HW + ppb + px;
    float acc[16];
    #pragma unroll
    for (int j = 0; j < 16; ++j) acc[j] = 0.f;
    for (int ci = 0; ci < 64; ++ci) {
        float xv = fb[(size_t)ci * HW];
        const float4* wr = (const float4*)wsh[grp * 64 + ci];
        #pragma unroll
        for (int q = 0; q < 4; ++q) {
            float4 wv = wr[q];
            acc[q*4+0] += wv.x*xv; acc[q*4+1] += wv.y*xv;
            acc[q*4+2] += wv.z*xv; acc[q*4+3] += wv.w*xv;
        }
    }
    #pragma unroll
    for (int j = 0; j < 16; ++j) part[grp][px][j] = acc[j];
    __syncthreads();
    for (int e = tid; e < 64 * INNER; e += 256) {
        int co = e >> 6, p2 = e & 63;
        float v = part[0][p2][co] + part[1][p2][co] + part[2][p2][co] +
                  part[3][p2][co] + bias[co];
        xr[(size_t)(b * INNER + co) * HW + ppb + p2] = v;
    }
}

// ------- dilated 3x3 conv + 6 spatial-transform products -> feats (252 ch) ----
__global__ __launch_bounds__(256)
void k_dil(const float* __restrict__ xr, const float* __restrict__ dw,
           const float* __restrict__ db, float* __restrict__ feats) {
    int bid = blockIdx.x;
    const int hb = bid % 36; bid /= 36;
    const int oc = bid % 14; bid /= 14;
    const int b  = bid & 1;  bid >>= 1;
    const int d  = bid;              // 0..2
    const int dil = d + 1;
    __shared__ float wsh[126];
    const int tid = threadIdx.x;
    if (tid < 126) wsh[tid] = dw[(d * 14 + oc) * 126 + tid];
    __syncthreads();
    const int p = hb * 256 + tid;
    const int h = p / 96, w = p - (p / 96) * 96;
    const float* xb = xr + (size_t)b * INNER * HW;
    float acc = db[d * 14 + oc];
    for (int ic = 0; ic < 14; ++ic) {
        const float* xc = xb + (size_t)ic * HW;
        #pragma unroll
        for (int kh = 0; kh < 3; ++kh) {
            int ih = h + (kh - 1) * dil;
            if (ih < 0 || ih >= 96) continue;
            #pragma unroll
            for (int kw = 0; kw < 3; ++kw) {
                int iw = w + (kw - 1) * dil;
                if (iw < 0 || iw >= 96) continue;
                acc += xc[ih * 96 + iw] * wsh[ic * 9 + kh * 3 + kw];
            }
        }
    }
    const float* xo = xb + (size_t)oc * HW;
    const int H1 = 95;
    float t0 = xo[h * 96 + w];
    float t1 = xo[h * 96 + (H1 - w)];
    float t2 = xo[(H1 - h) * 96 + w];
    float t3 = xo[w * 96 + (H1 - h)];
    float t4 = xo[(H1 - h) * 96 + (H1 - w)];
    float t5 = xo[(H1 - w) * 96 + h];
    float* fo = feats + (size_t)b * NF * HW;
    const int ch0 = d * 6 * 14 + oc;
    fo[(size_t)(ch0 + 0 * 14) * HW + p] = acc * t0;
    fo[(size_t)(ch0 + 1 * 14) * HW + p] = acc * t1;
    fo[(size_t)(ch0 + 2 * 14) * HW + p] = acc * t2;
    fo[(size_t)(ch0 + 3 * 14) * HW + p] = acc * t3;
    fo[(size_t)(ch0 + 4 * 14) * HW + p] = acc * t4;
    fo[(size_t)(ch0 + 5 * 14) * HW + p] = acc * t5;
}

// ------- transpose: tok_c bf16 [C][HW] -> tok_t bf16 [HW][C] -------
__global__ __launch_bounds__(256)
void k_tr(const unsigned short* __restrict__ tc, unsigned short* __restrict__ tt) {
    const int tid = threadIdx.x;
    int bid = blockIdx.x;
    const int b = bid / 576;
    const int r = bid - b * 576;          // 0..575
    const int t0 = (r >> 2) * 64;
    const int c0 = (r & 3) * 64;
    __shared__ unsigned int T[64][37];
    const unsigned short* tcb = tc + (size_t)b * CHW;
    unsigned short* ttb = tt + (size_t)b * CHW;
    for (int e = tid; e < 2048; e += 256) {
        int to = e & 63, chp = e >> 6;
        unsigned int v0 = tcb[(size_t)(c0 + 2*chp)     * HW + t0 + to];
        unsigned int v1 = tcb[(size_t)(c0 + 2*chp + 1) * HW + t0 + to];
        T[to][chp] = (v1 << 16) | v0;
    }
    __syncthreads();
    for (int e = tid; e < 2048; e += 256) {
        int to = e >> 5, chp = e & 31;
        ((unsigned int*)(ttb + (size_t)(t0 + to) * CH + c0))[chp] = T[to][chp];
    }
}

// ---------------- bf16 MFMA flash attention, 2 key-strips ----------------
// 576 blocks (288 qb x 2 strips), 256 thr (4 waves x 16 q), KV tile 64 keys.
// Single-buffer LDS, reg-staged with async load split (T14); partials to ws.
#define KTILE 64
#define NSTRIP 2
#define TPS 72           // tiles per strip

__device__ __forceinline__ unsigned int pk_bf16(float lo, float hi) {
    unsigned int l = __bfloat16_as_ushort(__float2bfloat16(lo));
    unsigned int h = __bfloat16_as_ushort(__float2bfloat16(hi));
    return (h << 16) | l;
}

__global__ __launch_bounds__(256, 2)
void k_attn2(const unsigned short* __restrict__ tok_t,
             const unsigned short* __restrict__ tok_c,
             unsigned short* __restrict__ opart, float* __restrict__ oml) {
    __shared__ unsigned short Kt[64][256];   // [key][ch ^ ((key&7)<<3)]
    __shared__ unsigned short Vt[256][64];   // [ch][key ^ ((ch&7)<<3)]
    __shared__ unsigned short Psh[4][16][72];
    const int tid  = threadIdx.x;
    const int wid  = tid >> 6;
    const int lane = tid & 63;
    const int lq   = lane & 15;
    const int lg   = lane >> 4;

    const int blk   = blockIdx.x;
    const int rb    = blk % 288;
    const int strip = blk / 288;                   // 0 or 1
    const int qb    = (rb & 7) * 36 + (rb >> 3);   // XCD-grouped
    const int b     = qb / 144;
    const int q0    = (qb - b * 144) * 64;
    const unsigned short* tt = tok_t + (size_t)b * CHW;
    const unsigned short* tc = tok_c + (size_t)b * CHW;

    // Q fragments (B-operand of S^T): col=q=lq, k = ks*32 + 8*lg + j
    s16x8 qf[8];
    {
        const unsigned short* qrow = tt + (size_t)(q0 + wid*16 + lq) * CH + 8*lg;
        #pragma unroll
        for (int ks = 0; ks < 8; ++ks)
            qf[ks] = *(const s16x8*)(qrow + 32*ks);
    }
    float m_r = -1e30f, l_r = 0.f;
    f32x4 oacc[16];
    #pragma unroll
    for (int ct = 0; ct < 16; ++ct) oacc[ct] = (f32x4){0.f,0.f,0.f,0.f};

    // staging decode (per-thread, compile-time unrolled)
    s16x8 rk[8], rv[8];
    const int t0k = strip * TPS;
    {   // prologue: load tile t0k into regs
        const int k0 = t0k * KTILE;
        #pragma unroll
        for (int i = 0; i < 8; ++i) {
            int e = i * 256 + tid;
            int key = e >> 5, cho = (e & 31) * 8;
            rk[i] = *(const s16x8*)(tt + (size_t)(k0 + key) * CH + cho);
            int ch = e >> 3, ko = (e & 7) * 8;
            rv[i] = *(const s16x8*)(tc + (size_t)ch * HW + k0 + ko);
        }
    }

    for (int t = 0; t < TPS; ++t) {
        __syncthreads();   // prior tile's LDS reads complete
        // ---- ds_write staged tile (swizzled) ----
        #pragma unroll
        for (int i = 0; i < 8; ++i) {
            int e = i * 256 + tid;
            int key = e >> 5, cho = (e & 31) * 8;
            *(s16x8*)(&Kt[key][cho ^ ((key & 7) << 3)]) = rk[i];
            int ch = e >> 3, ko = (e & 7) * 8;
            *(s16x8*)(&Vt[ch][ko ^ ((ch & 7) << 3)]) = rv[i];
        }
        __syncthreads();
        // ---- issue next tile's loads (hidden under compute) ----
        if (t + 1 < TPS) {
            const int kn = (t0k + t + 1) * KTILE;
            #pragma unroll
            for (int i = 0; i < 8; ++i) {
                int e = i * 256 + tid;
                int key = e >> 5, cho = (e & 31) * 8;
                rk[i] = *(const s16x8*)(tt + (size_t)(kn + key) * CH + cho);
                int ch = e >> 3, ko = (e & 7) * 8;
                rv[i] = *(const s16x8*)(tc + (size_t)ch * HW + kn + ko);
            }
        }
        // ---- S^T = K·Q^T : 4 key-subtiles ----
        float s[16];
        #pragma unroll
        for (int mt = 0; mt < 4; ++mt) {
            f32x4 acc = (f32x4){0.f,0.f,0.f,0.f};
            const int key = mt * 16 + lq;
            const int sw  = (key & 7) << 3;
            #pragma unroll
            for (int ks = 0; ks < 8; ++ks) {
                s16x8 af = *(const s16x8*)(&Kt[key][(ks*32 + 8*lg) ^ sw]);
                acc = __builtin_amdgcn_mfma_f32_16x16x32_bf16(af, qf[ks], acc, 0, 0, 0);
            }
            #pragma unroll
            for (int r = 0; r < 4; ++r) s[mt*4 + r] = acc[r] * SL2E;
        }
        // ---- online softmax (exp2 domain, defer-max) ----
        float tm = s[0];
        #pragma unroll
        for (int i = 1; i < 16; ++i) tm = fmaxf(tm, s[i]);
        tm = fmaxf(tm, __shfl_xor(tm, 16));
        tm = fmaxf(tm, __shfl_xor(tm, 32));
        const float mn = fmaxf(m_r, tm);
        if (!__all(mn - m_r <= 8.0f)) {
            const float alpha = exp2f(m_r - mn);
            m_r = mn;
            l_r *= alpha;
            #pragma unroll
            for (int ct = 0; ct < 16; ++ct) {
                oacc[ct][0] *= alpha; oacc[ct][1] *= alpha;
                oacc[ct][2] *= alpha; oacc[ct][3] *= alpha;
            }
        }
        float ps = 0.f;
        #pragma unroll
        for (int i = 0; i < 16; ++i) { s[i] = exp2f(s[i] - m_r); ps += s[i]; }
        ps += __shfl_xor(ps, 16);
        ps += __shfl_xor(ps, 32);
        l_r += ps;
        // ---- P -> per-wave LDS ----
        #pragma unroll
        for (int kt = 0; kt < 4; ++kt) {
            *(unsigned int*)&Psh[wid][lq][16*kt + 4*lg]     = pk_bf16(s[kt*4+0], s[kt*4+1]);
            *(unsigned int*)&Psh[wid][lq][16*kt + 4*lg + 2] = pk_bf16(s[kt*4+2], s[kt*4+3]);
        }
        s16x8 pb0 = *(const s16x8*)&Psh[wid][lq][8*lg];
        s16x8 pb1 = *(const s16x8*)&Psh[wid][lq][32 + 8*lg];
        // ---- PV: out^T[ch][q] ----
        #pragma unroll
        for (int ct = 0; ct < 16; ++ct) {
            const int ch = ct * 16 + lq;
            const int sw = (ch & 7) << 3;
            s16x8 va0 = *(const s16x8*)(&Vt[ch][(8*lg) ^ sw]);
            s16x8 va1 = *(const s16x8*)(&Vt[ch][(32 + 8*lg) ^ sw]);
            oacc[ct] = __builtin_amdgcn_mfma_f32_16x16x32_bf16(va0, pb0, oacc[ct], 0, 0, 0);
            oacc[ct] = __builtin_amdgcn_mfma_f32_16x16x32_bf16(va1, pb1, oacc[ct], 0, 0, 0);
        }
    }
    // ---- epilogue: normalized bf16 partial + (m,l) ----
    const float linv = 1.f / l_r;
    const int qi = (strip * 288 + qb) * 64 + wid * 16 + lq;
    unsigned short* op = opart + (size_t)qi * CH;
    #pragma unroll
    for (int ct = 0; ct < 16; ++ct) {
        const int ch0 = ct * 16 + 4 * lg;
        unsigned int* dst = (unsigned int*)(op + ch0);
        dst[0] = pk_bf16(oacc[ct][0] * linv, oacc[ct][1] * linv);
        dst[1] = pk_bf16(oacc[ct][2] * linv, oacc[ct][3] * linv);
    }
    if (lg == 0) {
        oml[(size_t)qi * 2 + 0] = m_r;
        oml[(size_t)qi * 2 + 1] = l_r;
    }
}

// ------- merge 2 strips + residual -> out -------
__global__ __launch_bounds__(256)
void k_merge(const unsigned short* __restrict__ opart, const float* __restrict__ oml,
             const float* __restrict__ fmap, float* __restrict__ outp) {
    const int qb  = blockIdx.x;          // 0..287
    const int b   = qb / 144;
    const int q0g = (qb - b * 144) * 64;
    const int q   = threadIdx.x & 63;
    const int p   = threadIdx.x >> 6;    // 0..3: 64-ch group
    const int qi0 = qb * 64 + q;
    const int qi1 = (288 + qb) * 64 + q;
    const float m0 = oml[(size_t)qi0*2], l0 = oml[(size_t)qi0*2+1];
    const float m1 = oml[(size_t)qi1*2], l1 = oml[(size_t)qi1*2+1];
    const float m  = fmaxf(m0, m1);
    float w0 = exp2f(m0 - m) * l0;
    float w1 = exp2f(m1 - m) * l1;
    const float inv = 1.f / (w0 + w1);
    w0 *= inv; w1 *= inv;
    const unsigned short* o0 = opart + (size_t)qi0 * CH;
    const unsigned short* o1 = opart + (size_t)qi1 * CH;
    const float* fb = fmap + (size_t)b * CHW;
    float* ob = outp + (size_t)b * CHW;
    #pragma unroll 4
    for (int j = 0; j < 16; ++j) {
        const int ch = p * 64 + j * 4;
        ushort4 a = *(const ushort4*)(o0 + ch);
        ushort4 c = *(const ushort4*)(o1 + ch);
        float av[4] = {
            __uint_as_float((unsigned)a.x << 16), __uint_as_float((unsigned)a.y << 16),
            __uint_as_float((unsigned)a.z << 16), __uint_as_float((unsigned)a.w << 16)};
        float cv[4] = {
            __uint_as_float((unsigned)c.x << 16), __uint_as_float((unsigned)c.y << 16),
            __uint_as_float((unsigned)c.z << 16), __uint_as_float((unsigned)c.w << 16)};
        #pragma unroll
        for (int r = 0; r < 4; ++r) {
            const size_t g = (size_t)(ch + r) * HW + q0g + q;
            ob[g] = fb[g] + 0.2f * (w0 * av[r] + w1 * cv[r]);
        }
    }
}

extern "C" void kernel_launch(void* const* d_in, const int* in_sizes, int n_in,
                              void* d_out, int out_size, void* d_ws, size_t ws_size,
                              hipStream_t stream) {
    const float* x        = (const float*)d_in[0];
    const float* proj_w   = (const float*)d_in[1];
    const float* proj_b   = (const float*)d_in[2];
    const float* reduce_w = (const float*)d_in[3];
    const float* reduce_b = (const float*)d_in[4];
    const float* dil_w    = (const float*)d_in[5];
    const float* dil_b    = (const float*)d_in[6];
    const float* fuse_w   = (const float*)d_in[7];
    const float* fuse_b   = (const float*)d_in[8];
    float* out = (float*)d_out;

    float* ws    = (float*)d_ws;
    float* fmap  = ws;                           // 4,718,592 f
    float* xr    = fmap + 4718592;               //   258,048 f
    float* feats = xr + 258048;                  // 4,644,864 f
    unsigned short* tok_c = (unsigned short*)(feats + 4644864);   // 4,718,592 u16
    unsigned short* tok_t = tok_c + 4718592;                      // 4,718,592 u16
    unsigned short* opart = tok_t + 4718592;                      // 9,437,184 u16
    float* oml = (float*)(opart + 9437184);                       //    73,728 f

    k_conv1x1<256, float><<<dim3(36, 8), 256, 0, stream>>>(x, proj_w, proj_b, fmap);
    k_reduce<<<288, 256, 0, stream>>>(fmap, reduce_w, reduce_b, xr);
    k_dil<<<3024, 256, 0, stream>>>(xr, dil_w, dil_b, feats);
    k_conv1x1<252, __hip_bfloat16><<<dim3(36, 8), 256, 0, stream>>>(
        feats, fuse_w, fuse_b, (__hip_bfloat16*)tok_c);
    k_tr<<<1152, 256, 0, stream>>>(tok_c, tok_t);
    k_attn2<<<576, 256, 0, stream>>>(tok_t, tok_c, opart, oml);
    k_merge<<<288, 256, 0, stream>>>(opart, oml, fmap, out);
}